// Round 4
// baseline (365.231 us; speedup 1.0000x reference)
//
#include <hip/hip_runtime.h>

// B=64, S=512, D=256, VOCAB=50000, NC=10, N_STEPS=10 (h=0.1), BN eval.
// z_final = z0 @ P10 + c10, P10 = M^10, M = Taylor4(exp(hA)), A = W^T.
// Transpose trick: M = N^T, N = I + B, B = 0.1W + 0.005W^2 + (1e-3/6)W^3 + (1e-4/24)W^4,
// so P10 = (N^10)^T; the transpose is absorbed into the slab fragment scatter.
//
// KEY LESSON (rounds 1-3): prep cost is ~13-18us PER DISPATCH BOUNDARY, not
// kernel bodies (12->8 dispatches with 4x faster bodies changed nothing).
// cg::grid.sync is worse (~110us/sync). So: minimize dispatches via row-chaining
// (row i of X@Y needs only row i of X + full Y):
//   d1 k_prep1: per-block W[i]->W2[i]->W3[i]->W4[i] -> B row + c1[i]
//               (+ conv repack / featbuf+done zero on spare blocks)
//   d2 k_prep2: N2 = I + 2B + B^2
//   d3 k_prep3: N10[i] = N2[i]@(N2)^4 -> slab node part; block 256: c-chain -> c10
//   d4 k_main:  (proven round-1 structure) + finisher-block classifier
//               (device-scope done-counter; atomicMax(p,0) coherent reads)
// 10 dispatches -> 4.

typedef short bf16x8 __attribute__((ext_vector_type(8)));
typedef float f32x4 __attribute__((ext_vector_type(4)));

__device__ __forceinline__ unsigned short f2bf(float f) {
  unsigned u = __float_as_uint(f);
  u += 0x7FFFu + ((u >> 16) & 1u);   // RNE; inputs are normal floats
  return (unsigned short)(u >> 16);
}

// acc_j = sum_k xrow[k] * Y[k][tid]; xrow in LDS, Y global, coalesced.
// 16 loads in flight per thread, outer unroll 4.
__device__ __forceinline__ float dotcol(const float* __restrict__ xrow,
                                        const float* __restrict__ Y, int tid) {
  float a0 = 0.f, a1 = 0.f, a2 = 0.f, a3 = 0.f;
#pragma unroll 4
  for (int k = 0; k < 256; k += 16) {
    float bv[16];
#pragma unroll
    for (int u = 0; u < 16; ++u) bv[u] = Y[(k + u) * 256 + tid];
#pragma unroll
    for (int u = 0; u < 16; u += 4) {
      a0 = fmaf(xrow[k + u + 0], bv[u + 0], a0);
      a1 = fmaf(xrow[k + u + 1], bv[u + 1], a1);
      a2 = fmaf(xrow[k + u + 2], bv[u + 2], a2);
      a3 = fmaf(xrow[k + u + 3], bv[u + 3], a3);
    }
  }
  return (a0 + a1) + (a2 + a3);
}

// init + sum_k cvec[k] * row[k]; cvec in LDS, row = one global row (per-thread).
__device__ __forceinline__ float rowscan(const float* __restrict__ cvec,
                                         const float* __restrict__ row, float init) {
  float a0 = init, a1 = 0.f, a2 = 0.f, a3 = 0.f;
#pragma unroll 4
  for (int k = 0; k < 256; k += 16) {
    float bv[16];
#pragma unroll
    for (int u = 0; u < 16; ++u) bv[u] = row[k + u];
#pragma unroll
    for (int u = 0; u < 16; u += 4) {
      a0 = fmaf(cvec[k + u + 0], bv[u + 0], a0);
      a1 = fmaf(cvec[k + u + 1], bv[u + 1], a1);
      a2 = fmaf(cvec[k + u + 2], bv[u + 2], a2);
      a3 = fmaf(cvec[k + u + 3], bv[u + 3], a3);
    }
  }
  return (a0 + a1) + (a2 + a3);
}

// ---- d1: blocks 0-255: W-power row chain -> B row + c1[i].
//          blocks 256-639: conv repack + featbuf/done zero.
__global__ __launch_bounds__(256) void k_prep1(
    const float* __restrict__ W, const float* __restrict__ bode,
    const float* __restrict__ w3, const float* __restrict__ w4c, const float* __restrict__ w5,
    float* __restrict__ B, float* __restrict__ c1,
    unsigned short* __restrict__ slab, unsigned* __restrict__ featbuf) {
  __shared__ float r1[256], r2[256], r3[256], red[4];
  const int tid = threadIdx.x, blk = blockIdx.x;
  if (blk < 256) {
    const int i = blk;
    r1[tid] = W[i * 256 + tid];
    __syncthreads();
    const float v2 = dotcol(r1, W, tid);   // W^2[i][tid]
    r2[tid] = v2;
    __syncthreads();
    const float v3 = dotcol(r2, W, tid);   // W^3[i][tid]
    r3[tid] = v3;
    __syncthreads();
    const float v4 = dotcol(r3, W, tid);   // W^4[i][tid]
    const float w1 = r1[tid];
    B[i * 256 + tid] = 0.1f * w1 + 0.005f * v2
                     + (0.001f / 6.f) * v3 + (0.0001f / 24.f) * v4;
    // c1[i] = 0.1*(b[i] + sum_k b[k]*(0.05 W[i,k] + (0.01/6) W2[i,k] + (0.001/24) W3[i,k]))
    const float q = 0.05f * w1 + (0.01f / 6.f) * v2 + (0.001f / 24.f) * v3;
    float val = bode[tid] * q;
#pragma unroll
    for (int off = 32; off > 0; off >>= 1) val += __shfl_down(val, off);
    if ((tid & 63) == 0) red[tid >> 6] = val;
    __syncthreads();
    if (tid == 0) c1[i] = 0.1f * (bode[i] + ((red[0] + red[1]) + (red[2] + red[3])));
  } else {
    const int base = (blk - 256) * 256 + tid;   // 0..98303
#pragma unroll
    for (int u = 0; u < 4; ++u) {
      int e = base + u * 98304;                 // covers 0..393215 = 12*32768
      int s = e >> 15, r = e & 32767, kd = r >> 7, o = r & 127;
      const float* w; int k, j;
      if (s < 3)      { w = w3;  k = 3; j = s; }
      else if (s < 7) { w = w4c; k = 4; j = s - 3; }
      else            { w = w5;  k = 5; j = s - 7; }
      float val = w[(o * 256 + kd) * k + j];    // w[o][d=kd][j], shape (128,256,k)
      int kc = kd >> 5, quad = (kd >> 3) & 3, q8 = kd & 7;
      slab[s * 32768 + ((kc * 4 + quad) * 128 + o) * 8 + q8] = f2bf(val);
    }
    if (base <= 64 * 640) featbuf[base] = 0u;   // includes done counter at [40960]
  }
}

// ---- d2: N2 = I + 2B + B^2
__global__ __launch_bounds__(256) void k_prep2(const float* __restrict__ B,
                                               float* __restrict__ N2) {
  __shared__ float xrow[256];
  const int tid = threadIdx.x, i = blockIdx.x;
  xrow[tid] = B[i * 256 + tid];
  __syncthreads();
  const float s = dotcol(xrow, B, tid);
  N2[i * 256 + tid] = ((i == tid) ? 1.f : 0.f) + 2.f * xrow[tid] + s;
}

// ---- d3: blocks 0-255: N10[i] = N2[i]@(N2)^4 -> slab node scatter.
//          block 256: c2 = 2c1 + c1.B-rows; 4x: c <- c.(N2)-rows + c2 -> c10.
__global__ __launch_bounds__(256) void k_prep3(
    const float* __restrict__ B, const float* __restrict__ N2,
    const float* __restrict__ c1, float* __restrict__ c10,
    unsigned short* __restrict__ slab) {
  __shared__ float xr[256], c2s[256];
  const int tid = threadIdx.x, blk = blockIdx.x;
  if (blk < 256) {
    xr[tid] = N2[blk * 256 + tid];
    __syncthreads();
    float v = 0.f;
#pragma unroll 1
    for (int it = 0; it < 4; ++it) {
      v = dotcol(xr, N2, tid);
      __syncthreads();
      xr[tid] = v;
      __syncthreads();
    }
    // v = N10[o=blk][kd=tid] = P10[kd][o]
    const int o = blk, kd = tid;
    const int kc = kd >> 5, quad = (kd >> 3) & 3, q8 = kd & 7;
    slab[(12 + (o >> 7)) * 32768 + ((kc * 4 + quad) * 128 + (o & 127)) * 8 + q8] = f2bf(v);
  } else {
    const int j = tid;
    xr[tid] = c1[tid];
    __syncthreads();
    // c2[j] = 2*c1[j] + sum_k c1[k]*B[j][k]
    float acc = rowscan(xr, B + (size_t)j * 256, 2.f * xr[j]);
    __syncthreads();
    xr[j] = acc; c2s[j] = acc;
    __syncthreads();
    // c_{k+2} = c_k @ M^2 + c2 ; (c@M^2)[j] = sum_k c[k]*N2[j][k] (I included)
#pragma unroll 1
    for (int it = 0; it < 4; ++it) {
      float a = rowscan(xr, N2 + (size_t)j * 256, c2s[j]);
      __syncthreads();
      xr[j] = a;
      __syncthreads();
    }
    c10[j] = xr[j];
  }
}

// ---------------- fused main kernel (round-1 structure + finisher) ----------------
// grid 512 = 64 batches x 8 t-chunks of 64. 256 threads = 4 waves.
// LDS: X tile 68 x 264 bf16; B tile 2 x 16 KB double-buffered.
// Per iteration: issue next-stage loads -> 16 MFMA from Bt[cur] -> epilogue at
// group ends -> ds_write Bt[cur^1] -> ONE barrier.
// After the loop: device-scope done-counter; the 512th block runs the classifier
// (featbuf read via atomicMax(p,0) = coherent read) -> removes the k_fin dispatch.

__global__ __launch_bounds__(256, 2) void k_main(
    const int* __restrict__ ids, const float* __restrict__ emb,
    const unsigned short* __restrict__ slab, const float* __restrict__ ctot,
    const float* __restrict__ b3, const float* __restrict__ g3, const float* __restrict__ be3,
    const float* __restrict__ b4, const float* __restrict__ g4, const float* __restrict__ be4,
    const float* __restrict__ b5, const float* __restrict__ g5, const float* __restrict__ be5,
    unsigned* __restrict__ featbuf, const float* __restrict__ wc,
    const float* __restrict__ bc, float* __restrict__ out) {
  __shared__ alignas(16) unsigned short Xt[68 * 264];
  __shared__ alignas(16) unsigned short Bt[2][8192];
  __shared__ int ids_s[68];
  __shared__ unsigned lastf;
  const int tid = threadIdx.x;
  const int blk = blockIdx.x;
  const int b = blk >> 3;
  const int t0 = (blk & 7) * 64;
  const int lane = tid & 63;
  const int wave = tid >> 6;
  const int m15 = lane & 15;
  const int quad = lane >> 4;

  if (tid < 68) {
    int t = t0 + tid;
    ids_s[tid] = (t < 512) ? ids[b * 512 + t] : -1;
  }
  __syncthreads();

  // issue entry-0 B-stage loads first; latency hides under the X gather
  const uint4* slab4 = (const uint4*)slab;
  uint4 st0 = slab4[tid];
  uint4 st1 = slab4[tid + 256];
  uint4 st2 = slab4[tid + 512];
  uint4 st3 = slab4[tid + 768];

  // gather + fp32->bf16 X tile (rows beyond S zero-filled)
  for (int i = tid; i < 68 * 64; i += 256) {
    int row = i >> 6, s4 = i & 63;
    uint2 v = make_uint2(0u, 0u);
    int id = ids_s[row];
    if (id >= 0) {
      const float4 f = *(const float4*)(emb + (size_t)id * 256 + s4 * 4);
      v.x = (unsigned)f2bf(f.x) | ((unsigned)f2bf(f.y) << 16);
      v.y = (unsigned)f2bf(f.z) | ((unsigned)f2bf(f.w) << 16);
    }
    *(uint2*)&Xt[row * 264 + s4 * 4] = v;
  }
  {
    uint4* dst = (uint4*)Bt[0] + tid;
    dst[0] = st0; dst[256] = st1; dst[512] = st2; dst[768] = st3;
  }
  __syncthreads();  // Xt + Bt[0] ready

  f32x4 acc[4][2];
#pragma unroll
  for (int mt = 0; mt < 4; ++mt)
#pragma unroll
    for (int nt = 0; nt < 2; ++nt) acc[mt][nt] = (f32x4){0.f, 0.f, 0.f, 0.f};

  int cur = 0;
  for (int e = 0; e < 56; ++e) {
    const int slice = e >> 2;
    const int kcq = e & 3;
    // conv shift = ji within group; node slices shift 0
    const int shift = (slice < 3) ? slice
                    : (slice < 7) ? (slice - 3)
                    : (slice < 12) ? (slice - 7) : 0;

    // prefetch next stage into regs (no wait until the ds_write below)
    if (e < 55) {
      const uint4* src = slab4 + (((e + 1) >> 2) * 4096 + ((e + 1) & 3) * 1024) + tid;
      st0 = src[0]; st1 = src[256]; st2 = src[512]; st3 = src[768];
    }

    const unsigned short* Bc = Bt[cur];
#pragma unroll
    for (int kc2 = 0; kc2 < 2; ++kc2) {
      const int kd0 = (kcq * 2 + kc2) * 32 + quad * 8;
      bf16x8 af[4];
#pragma unroll
      for (int mt = 0; mt < 4; ++mt)
        af[mt] = *(const bf16x8*)&Xt[(shift + mt * 16 + m15) * 264 + kd0];
#pragma unroll
      for (int nt = 0; nt < 2; ++nt) {
        const bf16x8 bfr =
            *(const bf16x8*)&Bc[((kc2 * 4 + quad) * 128 + (wave * 2 + nt) * 16 + m15) * 8];
#pragma unroll
        for (int mt = 0; mt < 4; ++mt)
          acc[mt][nt] = __builtin_amdgcn_mfma_f32_16x16x32_bf16(af[mt], bfr, acc[mt][nt], 0, 0, 0);
      }
    }

    // epilogue at group boundaries (registers + shuffles + atomics only)
    if (kcq == 3) {
      const int g = (e == 11) ? 0 : (e == 27) ? 1 : (e == 47) ? 2
                  : (e == 51) ? 3 : (e == 55) ? 4 : -1;
      if (g >= 0) {
        if (g < 3) {
          const int kk = g + 3;
          const float* bb  = (g == 0) ? b3 : (g == 1) ? b4 : b5;
          const float* gg  = (g == 0) ? g3 : (g == 1) ? g4 : g5;
          const float* bbe = (g == 0) ? be3 : (g == 1) ? be4 : be5;
          const int off = 256 + g * 128;   // feats: [node 256][p3 128][p4 128][p5 128]
          const int tmax = 512 - kk;
#pragma unroll
          for (int nt = 0; nt < 2; ++nt) {
            const int n = (wave * 2 + nt) * 16 + m15;
            const float sc = gg[n] * 0.9999950000375f;  // g * 1/sqrt(1+1e-5)
            const float sh = fmaf(sc, bb[n], bbe[n]);
            float mx = 0.f;  // relu floor doubles as init
#pragma unroll
            for (int mt = 0; mt < 4; ++mt)
#pragma unroll
              for (int r = 0; r < 4; ++r) {
                const int t = t0 + mt * 16 + quad * 4 + r;
                const float v = fmaf(sc, acc[mt][nt][r], sh);
                if (t <= tmax) mx = fmaxf(mx, v);
              }
            mx = fmaxf(mx, __shfl_xor(mx, 16));
            mx = fmaxf(mx, __shfl_xor(mx, 32));
            if (quad == 0) atomicMax(&featbuf[b * 640 + off + n], __float_as_uint(mx));
          }
        } else {
          const int base = (g == 3) ? 0 : 128;
#pragma unroll
          for (int nt = 0; nt < 2; ++nt) {
            const int n = (wave * 2 + nt) * 16 + m15;
            const float ct = ctot[base + n];
            float mx = -3.4e38f;
#pragma unroll
            for (int mt = 0; mt < 4; ++mt)
#pragma unroll
              for (int r = 0; r < 4; ++r)
                mx = fmaxf(mx, acc[mt][nt][r] + ct);
            mx = fmaxf(mx, __shfl_xor(mx, 16));
            mx = fmaxf(mx, __shfl_xor(mx, 32));
            if (quad == 0) {
              unsigned bits = __float_as_uint(mx);
              unsigned key = (bits & 0x80000000u) ? ~bits : (bits | 0x80000000u);  // order-preserving
              atomicMax(&featbuf[b * 640 + base + n], key);
            }
          }
        }
        // reset accumulators for the next group
#pragma unroll
        for (int mt = 0; mt < 4; ++mt)
#pragma unroll
          for (int nt = 0; nt < 2; ++nt) acc[mt][nt] = (f32x4){0.f, 0.f, 0.f, 0.f};
      }
    }

    // write next stage into the other buffer (vmcnt drain lands here,
    // after ~300+ cycles of MFMA/ds_read work), then a single barrier
    if (e < 55) {
      uint4* dst = (uint4*)Bt[cur ^ 1] + tid;
      dst[0] = st0; dst[256] = st1; dst[512] = st2; dst[768] = st3;
    }
    __syncthreads();
    cur ^= 1;
  }

  // -------- finisher: last block computes the classifier --------
  unsigned* done = featbuf + 64 * 640;
  __threadfence();                       // release our featbuf atomics
  if (tid == 0) lastf = atomicAdd(done, 1u);
  __syncthreads();
  if (lastf == 511u) {
    __threadfence();                     // acquire
    // 4 waves x 16 batches each; 640 feats / 64 lanes = 10 per lane
#pragma unroll 1
    for (int bi = 0; bi < 16; ++bi) {
      const int bq = wave * 16 + bi;
      float p[10];
#pragma unroll
      for (int c = 0; c < 10; ++c) p[c] = 0.f;
#pragma unroll 1
      for (int f = lane; f < 640; f += 64) {
        unsigned u = atomicMax(&featbuf[bq * 640 + f], 0u);   // coherent read
        float v;
        if (f < 256) v = (u & 0x80000000u) ? __uint_as_float(u ^ 0x80000000u)
                                           : __uint_as_float(~u);
        else v = __uint_as_float(u);
#pragma unroll
        for (int c = 0; c < 10; ++c) p[c] = fmaf(v, wc[c * 640 + f], p[c]);
      }
#pragma unroll
      for (int c = 0; c < 10; ++c) {
        float s = p[c];
#pragma unroll
        for (int off = 32; off > 0; off >>= 1) s += __shfl_down(s, off);
        if (lane == 0) out[bq * 10 + c] = s + bc[c];
      }
    }
  }
}

// ---------------- launcher ----------------
extern "C" void kernel_launch(void* const* d_in, const int* in_sizes, int n_in,
                              void* d_out, int out_size, void* d_ws, size_t ws_size,
                              hipStream_t stream) {
  (void)in_sizes; (void)n_in; (void)out_size; (void)ws_size;
  const int*   ids  = (const int*)d_in[0];
  const float* emb  = (const float*)d_in[1];
  const float* W    = (const float*)d_in[2];
  const float* bode = (const float*)d_in[3];
  const float* w3   = (const float*)d_in[4];
  const float* b3   = (const float*)d_in[5];
  const float* g3   = (const float*)d_in[6];
  const float* be3  = (const float*)d_in[7];
  const float* w4   = (const float*)d_in[8];
  const float* b4   = (const float*)d_in[9];
  const float* g4   = (const float*)d_in[10];
  const float* be4  = (const float*)d_in[11];
  const float* w5   = (const float*)d_in[12];
  const float* b5   = (const float*)d_in[13];
  const float* g5   = (const float*)d_in[14];
  const float* be5  = (const float*)d_in[15];
  const float* wc   = (const float*)d_in[16];
  const float* bc   = (const float*)d_in[17];
  float* out = (float*)d_out;

  float* wsf = (float*)d_ws;
  // ws layout (floats): B 0 | N2 65536 | c1 131072 | c10 131328 |
  // slab 131584 (14*32768 bf16 = 229376 floats) | featbuf 360960 (40961 uints)
  float* B   = wsf;
  float* N2  = wsf + 65536;
  float* c1  = wsf + 131072;
  float* c10 = wsf + 131328;
  unsigned short* slab = (unsigned short*)(wsf + 131584);
  unsigned* featbuf = (unsigned*)(wsf + 360960);

  hipLaunchKernelGGL(k_prep1, dim3(640), dim3(256), 0, stream,
                     W, bode, w3, w4, w5, B, c1, slab, featbuf);
  hipLaunchKernelGGL(k_prep2, dim3(256), dim3(256), 0, stream, B, N2);
  hipLaunchKernelGGL(k_prep3, dim3(257), dim3(256), 0, stream, B, N2, c1, c10, slab);
  hipLaunchKernelGGL(k_main, dim3(512), dim3(256), 0, stream,
                     ids, emb, slab, c10,
                     b3, g3, be3, b4, g4, be4, b5, g5, be5, featbuf, wc, bc, out);
}

// Round 5
// 223.177 us; speedup vs baseline: 1.6365x; 1.6365x over previous
//
#include <hip/hip_runtime.h>

// B=64, S=512, D=256, VOCAB=50000, NC=10, N_STEPS=10 (h=0.1), BN eval.
// z_final = z0 @ P10 + c10, P10 = M^10, M = Taylor4(exp(hA)), A = W^T.
// Transpose trick: M = N^T, N = I + B, B = 0.1W + 0.005W^2 + (1e-3/6)W^3 + (1e-4/24)W^4,
// so P10 = (N^10)^T; the transpose is absorbed into the slab fragment scatter.
//
// LESSONS:
//  - prep cost is dominated by dispatch boundaries (~15-20us each); cg grid.sync
//    is ~110us/sync (worse). 3-dispatch prep via row-chaining (round 4, proven).
//  - finisher-block classifier = 145us serialized-atomic tail (round 4). Use a
//    separate k_fin dispatch (round 1, proven).
//  - k_main round-1 was LDS-throughput-bound: 128KB LDS/CU/entry vs 155cyc MFMA
//    (MfmaUtil 17.5%). The staged B tile is read exactly ONCE per block -> LDS
//    staging is pure waste. This version reads B-fragments per-wave directly
//    from the L2-resident slab (already in B-frag order), depth-2 register
//    pipeline, ZERO barriers in the main loop.

typedef short bf16x8 __attribute__((ext_vector_type(8)));
typedef float f32x4 __attribute__((ext_vector_type(4)));

__device__ __forceinline__ unsigned short f2bf(float f) {
  unsigned u = __float_as_uint(f);
  u += 0x7FFFu + ((u >> 16) & 1u);   // RNE; inputs are normal floats
  return (unsigned short)(u >> 16);
}

// acc_j = sum_k xrow[k] * Y[k][tid]; xrow in LDS, Y global, coalesced.
__device__ __forceinline__ float dotcol(const float* __restrict__ xrow,
                                        const float* __restrict__ Y, int tid) {
  float a0 = 0.f, a1 = 0.f, a2 = 0.f, a3 = 0.f;
#pragma unroll 4
  for (int k = 0; k < 256; k += 16) {
    float bv[16];
#pragma unroll
    for (int u = 0; u < 16; ++u) bv[u] = Y[(k + u) * 256 + tid];
#pragma unroll
    for (int u = 0; u < 16; u += 4) {
      a0 = fmaf(xrow[k + u + 0], bv[u + 0], a0);
      a1 = fmaf(xrow[k + u + 1], bv[u + 1], a1);
      a2 = fmaf(xrow[k + u + 2], bv[u + 2], a2);
      a3 = fmaf(xrow[k + u + 3], bv[u + 3], a3);
    }
  }
  return (a0 + a1) + (a2 + a3);
}

// init + sum_k cvec[k] * row[k]; cvec in LDS, row = one global row (per-thread).
__device__ __forceinline__ float rowscan(const float* __restrict__ cvec,
                                         const float* __restrict__ row, float init) {
  float a0 = init, a1 = 0.f, a2 = 0.f, a3 = 0.f;
#pragma unroll 4
  for (int k = 0; k < 256; k += 16) {
    float bv[16];
#pragma unroll
    for (int u = 0; u < 16; ++u) bv[u] = row[k + u];
#pragma unroll
    for (int u = 0; u < 16; u += 4) {
      a0 = fmaf(cvec[k + u + 0], bv[u + 0], a0);
      a1 = fmaf(cvec[k + u + 1], bv[u + 1], a1);
      a2 = fmaf(cvec[k + u + 2], bv[u + 2], a2);
      a3 = fmaf(cvec[k + u + 3], bv[u + 3], a3);
    }
  }
  return (a0 + a1) + (a2 + a3);
}

// ---- d1: blocks 0-255: W-power row chain -> B row + c1[i].
//          blocks 256-639: conv repack + featbuf zero.
__global__ __launch_bounds__(256) void k_prep1(
    const float* __restrict__ W, const float* __restrict__ bode,
    const float* __restrict__ w3, const float* __restrict__ w4c, const float* __restrict__ w5,
    float* __restrict__ B, float* __restrict__ c1,
    unsigned short* __restrict__ slab, unsigned* __restrict__ featbuf) {
  __shared__ float r1[256], r2[256], r3[256], red[4];
  const int tid = threadIdx.x, blk = blockIdx.x;
  if (blk < 256) {
    const int i = blk;
    r1[tid] = W[i * 256 + tid];
    __syncthreads();
    const float v2 = dotcol(r1, W, tid);   // W^2[i][tid]
    r2[tid] = v2;
    __syncthreads();
    const float v3 = dotcol(r2, W, tid);   // W^3[i][tid]
    r3[tid] = v3;
    __syncthreads();
    const float v4 = dotcol(r3, W, tid);   // W^4[i][tid]
    const float w1 = r1[tid];
    B[i * 256 + tid] = 0.1f * w1 + 0.005f * v2
                     + (0.001f / 6.f) * v3 + (0.0001f / 24.f) * v4;
    // c1[i] = 0.1*(b[i] + sum_k b[k]*(0.05 W[i,k] + (0.01/6) W2[i,k] + (0.001/24) W3[i,k]))
    const float q = 0.05f * w1 + (0.01f / 6.f) * v2 + (0.001f / 24.f) * v3;
    float val = bode[tid] * q;
#pragma unroll
    for (int off = 32; off > 0; off >>= 1) val += __shfl_down(val, off);
    if ((tid & 63) == 0) red[tid >> 6] = val;
    __syncthreads();
    if (tid == 0) c1[i] = 0.1f * (bode[i] + ((red[0] + red[1]) + (red[2] + red[3])));
  } else {
    const int base = (blk - 256) * 256 + tid;   // 0..98303
#pragma unroll
    for (int u = 0; u < 4; ++u) {
      int e = base + u * 98304;                 // covers 0..393215 = 12*32768
      int s = e >> 15, r = e & 32767, kd = r >> 7, o = r & 127;
      const float* w; int k, j;
      if (s < 3)      { w = w3;  k = 3; j = s; }
      else if (s < 7) { w = w4c; k = 4; j = s - 3; }
      else            { w = w5;  k = 5; j = s - 7; }
      float val = w[(o * 256 + kd) * k + j];    // w[o][d=kd][j], shape (128,256,k)
      int kc = kd >> 5, quad = (kd >> 3) & 3, q8 = kd & 7;
      slab[s * 32768 + ((kc * 4 + quad) * 128 + o) * 8 + q8] = f2bf(val);
    }
    if (base < 64 * 640) featbuf[base] = 0u;
  }
}

// ---- d2: N2 = I + 2B + B^2
__global__ __launch_bounds__(256) void k_prep2(const float* __restrict__ B,
                                               float* __restrict__ N2) {
  __shared__ float xrow[256];
  const int tid = threadIdx.x, i = blockIdx.x;
  xrow[tid] = B[i * 256 + tid];
  __syncthreads();
  const float s = dotcol(xrow, B, tid);
  N2[i * 256 + tid] = ((i == tid) ? 1.f : 0.f) + 2.f * xrow[tid] + s;
}

// ---- d3: blocks 0-255: N10[i] = N2[i]@(N2)^4 -> slab node scatter.
//          block 256: c2 = 2c1 + c1.B-rows; 4x: c <- c.(N2)-rows + c2 -> c10.
__global__ __launch_bounds__(256) void k_prep3(
    const float* __restrict__ B, const float* __restrict__ N2,
    const float* __restrict__ c1, float* __restrict__ c10,
    unsigned short* __restrict__ slab) {
  __shared__ float xr[256], c2s[256];
  const int tid = threadIdx.x, blk = blockIdx.x;
  if (blk < 256) {
    xr[tid] = N2[blk * 256 + tid];
    __syncthreads();
    float v = 0.f;
#pragma unroll 1
    for (int it = 0; it < 4; ++it) {
      v = dotcol(xr, N2, tid);
      __syncthreads();
      xr[tid] = v;
      __syncthreads();
    }
    // v = N10[o=blk][kd=tid] = P10[kd][o]
    const int o = blk, kd = tid;
    const int kc = kd >> 5, quad = (kd >> 3) & 3, q8 = kd & 7;
    slab[(12 + (o >> 7)) * 32768 + ((kc * 4 + quad) * 128 + (o & 127)) * 8 + q8] = f2bf(v);
  } else {
    const int j = tid;
    xr[tid] = c1[tid];
    __syncthreads();
    // c2[j] = 2*c1[j] + sum_k c1[k]*B[j][k]
    float acc = rowscan(xr, B + (size_t)j * 256, 2.f * xr[j]);
    __syncthreads();
    xr[j] = acc; c2s[j] = acc;
    __syncthreads();
    // c_{k+2} = c_k @ M^2 + c2 ; (c@M^2)[j] = sum_k c[k]*N2[j][k] (I included)
#pragma unroll 1
    for (int it = 0; it < 4; ++it) {
      float a = rowscan(xr, N2 + (size_t)j * 256, c2s[j]);
      __syncthreads();
      xr[j] = a;
      __syncthreads();
    }
    c10[j] = xr[j];
  }
}

// ---------------- fused main kernel ----------------
// grid 512 = 64 batches x 8 t-chunks of 64. 256 threads = 4 waves.
// LDS: only the X tile (68 x 264 bf16). B-fragments are read per-wave directly
// from the slab (L2-resident, already in MFMA B-frag order) with a depth-2
// register pipeline (fA/fB alternation, prefetch e+2/e+3). No barriers in the
// main loop: each staged B element is consumed by exactly one wave, so LDS
// staging was pure overhead (round-1 was LDS-bound at 128KB/CU/entry).

__global__ __launch_bounds__(256, 2) void k_main(
    const int* __restrict__ ids, const float* __restrict__ emb,
    const unsigned short* __restrict__ slab, const float* __restrict__ ctot,
    const float* __restrict__ b3, const float* __restrict__ g3, const float* __restrict__ be3,
    const float* __restrict__ b4, const float* __restrict__ g4, const float* __restrict__ be4,
    const float* __restrict__ b5, const float* __restrict__ g5, const float* __restrict__ be5,
    unsigned* __restrict__ featbuf) {
  __shared__ alignas(16) unsigned short Xt[68 * 264];
  __shared__ int ids_s[68];
  const int tid = threadIdx.x;
  const int blk = blockIdx.x;
  const int b = blk >> 3;
  const int t0 = (blk & 7) * 64;
  const int lane = tid & 63;
  const int wave = tid >> 6;
  const int m15 = lane & 15;
  const int quad = lane >> 4;

  if (tid < 68) {
    int t = t0 + tid;
    ids_s[tid] = (t < 512) ? ids[b * 512 + t] : -1;
  }
  __syncthreads();
  // gather + fp32->bf16 X tile (rows beyond S zero-filled)
  for (int i = tid; i < 68 * 64; i += 256) {
    int row = i >> 6, s4 = i & 63;
    uint2 v = make_uint2(0u, 0u);
    int id = ids_s[row];
    if (id >= 0) {
      const float4 f = *(const float4*)(emb + (size_t)id * 256 + s4 * 4);
      v.x = (unsigned)f2bf(f.x) | ((unsigned)f2bf(f.y) << 16);
      v.y = (unsigned)f2bf(f.z) | ((unsigned)f2bf(f.w) << 16);
    }
    *(uint2*)&Xt[row * 264 + s4 * 4] = v;
  }
  __syncthreads();  // Xt ready; no further barriers

  // per-lane B-fragment bases (bf16 units); frag(e,kc2,nt) = fb[nt] + e*8192 + kc2*4096
  const unsigned short* fb0 = slab + ((size_t)quad * 128 + (wave * 2 + 0) * 16 + m15) * 8;
  const unsigned short* fb1 = fb0 + 128;   // nt=1: +16*8

  bf16x8 fA[4], fB[4];   // [kc2*2+nt]
#pragma unroll
  for (int q = 0; q < 4; ++q) {
    fA[q] = *(const bf16x8*)(((q & 1) ? fb1 : fb0) + (q >> 1) * 4096);
    fB[q] = *(const bf16x8*)(((q & 1) ? fb1 : fb0) + 8192 + (q >> 1) * 4096);
  }

  f32x4 acc[4][2];
#pragma unroll
  for (int mt = 0; mt < 4; ++mt)
#pragma unroll
    for (int nt = 0; nt < 2; ++nt) acc[mt][nt] = (f32x4){0.f, 0.f, 0.f, 0.f};

#define ENTRY(KCQ, FR)                                                          \
  {                                                                             \
    _Pragma("unroll")                                                           \
    for (int kc2 = 0; kc2 < 2; ++kc2) {                                         \
      const int kd0 = ((KCQ) * 2 + kc2) * 32 + quad * 8;                        \
      bf16x8 af[4];                                                             \
      _Pragma("unroll")                                                         \
      for (int mt = 0; mt < 4; ++mt)                                            \
        af[mt] = *(const bf16x8*)&Xt[(shift + mt * 16 + m15) * 264 + kd0];      \
      _Pragma("unroll")                                                         \
      for (int mt = 0; mt < 4; ++mt) {                                          \
        acc[mt][0] = __builtin_amdgcn_mfma_f32_16x16x32_bf16(af[mt], FR[kc2 * 2 + 0], acc[mt][0], 0, 0, 0); \
        acc[mt][1] = __builtin_amdgcn_mfma_f32_16x16x32_bf16(af[mt], FR[kc2 * 2 + 1], acc[mt][1], 0, 0, 0); \
      }                                                                         \
    }                                                                           \
  }

  for (int ep = 0; ep < 28; ++ep) {
    const int e0 = ep * 2;
    const int slice = e0 >> 2;             // e0,e0+1 share slice (e0 even)
    const int shift = (slice < 3) ? slice
                    : (slice < 7) ? (slice - 3)
                    : (slice < 12) ? (slice - 7) : 0;
    const int kcq0 = e0 & 3;

    ENTRY(kcq0, fA);
    if (ep < 27) {
      const int eo = (e0 + 2) * 8192;
#pragma unroll
      for (int q = 0; q < 4; ++q)
        fA[q] = *(const bf16x8*)(((q & 1) ? fb1 : fb0) + eo + (q >> 1) * 4096);
    }
    ENTRY(kcq0 + 1, fB);
    if (ep < 27) {
      const int eo = (e0 + 3) * 8192;
#pragma unroll
      for (int q = 0; q < 4; ++q)
        fB[q] = *(const bf16x8*)(((q & 1) ? fb1 : fb0) + eo + (q >> 1) * 4096);
    }

    // epilogue at group boundaries: ep 5 (conv3), 13 (conv4), 23 (conv5),
    // 25 (node lo), 27 (node hi)
    const int g = (ep == 5) ? 0 : (ep == 13) ? 1 : (ep == 23) ? 2
                : (ep == 25) ? 3 : (ep == 27) ? 4 : -1;
    if (g >= 0) {
      if (g < 3) {
        const int kk = g + 3;
        const float* bb  = (g == 0) ? b3 : (g == 1) ? b4 : b5;
        const float* gg  = (g == 0) ? g3 : (g == 1) ? g4 : g5;
        const float* bbe = (g == 0) ? be3 : (g == 1) ? be4 : be5;
        const int off = 256 + g * 128;     // feats: [node 256][p3 128][p4 128][p5 128]
        const int tmax = 512 - kk;
#pragma unroll
        for (int nt = 0; nt < 2; ++nt) {
          const int n = (wave * 2 + nt) * 16 + m15;
          const float sc = gg[n] * 0.9999950000375f;  // g * 1/sqrt(1+1e-5)
          const float sh = fmaf(sc, bb[n], bbe[n]);
          float mx = 0.f;  // relu floor doubles as init
#pragma unroll
          for (int mt = 0; mt < 4; ++mt)
#pragma unroll
            for (int r = 0; r < 4; ++r) {
              const int t = t0 + mt * 16 + quad * 4 + r;
              const float v = fmaf(sc, acc[mt][nt][r], sh);
              if (t <= tmax) mx = fmaxf(mx, v);
            }
          mx = fmaxf(mx, __shfl_xor(mx, 16));
          mx = fmaxf(mx, __shfl_xor(mx, 32));
          if (quad == 0) atomicMax(&featbuf[b * 640 + off + n], __float_as_uint(mx));
        }
      } else {
        const int base = (g == 3) ? 0 : 128;
#pragma unroll
        for (int nt = 0; nt < 2; ++nt) {
          const int n = (wave * 2 + nt) * 16 + m15;
          const float ct = ctot[base + n];
          float mx = -3.4e38f;
#pragma unroll
          for (int mt = 0; mt < 4; ++mt)
#pragma unroll
            for (int r = 0; r < 4; ++r)
              mx = fmaxf(mx, acc[mt][nt][r] + ct);
          mx = fmaxf(mx, __shfl_xor(mx, 16));
          mx = fmaxf(mx, __shfl_xor(mx, 32));
          if (quad == 0) {
            unsigned bits = __float_as_uint(mx);
            unsigned key = (bits & 0x80000000u) ? ~bits : (bits | 0x80000000u);  // order-preserving
            atomicMax(&featbuf[b * 640 + base + n], key);
          }
        }
      }
      // reset accumulators for the next group
#pragma unroll
      for (int mt = 0; mt < 4; ++mt)
#pragma unroll
        for (int nt = 0; nt < 2; ++nt) acc[mt][nt] = (f32x4){0.f, 0.f, 0.f, 0.f};
    }
  }
#undef ENTRY
}

// ---------------- classifier ----------------
__global__ void k_fin(const unsigned* __restrict__ featbuf, const float* __restrict__ wc,
                      const float* __restrict__ bc, float* __restrict__ out) {
  int b = blockIdx.x, lane = threadIdx.x;  // 64 threads = 1 wave
  float p[10];
#pragma unroll
  for (int c = 0; c < 10; ++c) p[c] = 0.f;
  for (int f = lane; f < 640; f += 64) {
    unsigned u = featbuf[b * 640 + f];
    float v;
    if (f < 256) v = (u & 0x80000000u) ? __uint_as_float(u ^ 0x80000000u) : __uint_as_float(~u);
    else v = __uint_as_float(u);
#pragma unroll
    for (int c = 0; c < 10; ++c) p[c] = fmaf(v, wc[c * 640 + f], p[c]);
  }
#pragma unroll
  for (int c = 0; c < 10; ++c) {
    float s = p[c];
#pragma unroll
    for (int off = 32; off > 0; off >>= 1) s += __shfl_down(s, off);
    if (lane == 0) out[b * 10 + c] = s + bc[c];
  }
}

// ---------------- launcher ----------------
extern "C" void kernel_launch(void* const* d_in, const int* in_sizes, int n_in,
                              void* d_out, int out_size, void* d_ws, size_t ws_size,
                              hipStream_t stream) {
  (void)in_sizes; (void)n_in; (void)out_size; (void)ws_size;
  const int*   ids  = (const int*)d_in[0];
  const float* emb  = (const float*)d_in[1];
  const float* W    = (const float*)d_in[2];
  const float* bode = (const float*)d_in[3];
  const float* w3   = (const float*)d_in[4];
  const float* b3   = (const float*)d_in[5];
  const float* g3   = (const float*)d_in[6];
  const float* be3  = (const float*)d_in[7];
  const float* w4   = (const float*)d_in[8];
  const float* b4   = (const float*)d_in[9];
  const float* g4   = (const float*)d_in[10];
  const float* be4  = (const float*)d_in[11];
  const float* w5   = (const float*)d_in[12];
  const float* b5   = (const float*)d_in[13];
  const float* g5   = (const float*)d_in[14];
  const float* be5  = (const float*)d_in[15];
  const float* wc   = (const float*)d_in[16];
  const float* bc   = (const float*)d_in[17];
  float* out = (float*)d_out;

  float* wsf = (float*)d_ws;
  // ws layout (floats): B 0 | N2 65536 | c1 131072 | c10 131328 |
  // slab 131584 (14*32768 bf16 = 229376 floats) | featbuf 360960 (40960 uints)
  float* B   = wsf;
  float* N2  = wsf + 65536;
  float* c1  = wsf + 131072;
  float* c10 = wsf + 131328;
  unsigned short* slab = (unsigned short*)(wsf + 131584);
  unsigned* featbuf = (unsigned*)(wsf + 360960);

  hipLaunchKernelGGL(k_prep1, dim3(640), dim3(256), 0, stream,
                     W, bode, w3, w4, w5, B, c1, slab, featbuf);
  hipLaunchKernelGGL(k_prep2, dim3(256), dim3(256), 0, stream, B, N2);
  hipLaunchKernelGGL(k_prep3, dim3(257), dim3(256), 0, stream, B, N2, c1, c10, slab);
  hipLaunchKernelGGL(k_main, dim3(512), dim3(256), 0, stream,
                     ids, emb, slab, c10,
                     b3, g3, be3, b4, g4, be4, b5, g5, be5, featbuf);
  hipLaunchKernelGGL(k_fin, dim3(64), dim3(64), 0, stream, featbuf, wc, bc, out);
}